// Round 1
// baseline (126.896 us; speedup 1.0000x reference)
//
#include <hip/hip_runtime.h>
#include <math.h>

#define BB 32
#define TT 4096
#define HH 512
#define QQS 512
#define TS 64            // t-splits for context partials
#define CH (TT / TS)     // 64 rows per partial block

__device__ inline float wave_reduce_sum(float v) {
#pragma unroll
    for (int off = 32; off > 0; off >>= 1) v += __shfl_xor(v, off, 64);
    return v;
}

__device__ inline float fast_tanh(float x) {
    x = fminf(fmaxf(x, -15.f), 15.f);
    float e = __expf(-2.f * x);
    return (1.f - e) / (1.f + e);
}

// q[b][h] = sum_s query[b][s] * Wq[h][s]; one wave per (b,h)
__global__ void qproj_kernel(const float* __restrict__ query,
                             const float* __restrict__ Wq,
                             float* __restrict__ qout) {
    int wid  = (blockIdx.x * blockDim.x + threadIdx.x) >> 6;
    int lane = threadIdx.x & 63;
    int b = wid >> 9;        // / HH
    int h = wid & (HH - 1);
    const float4* qr = (const float4*)(query + (size_t)b * QQS);
    const float4* wr = (const float4*)(Wq + (size_t)h * QQS);
    float4 a0 = qr[lane],      w0 = wr[lane];
    float4 a1 = qr[lane + 64], w1 = wr[lane + 64];
    float acc = a0.x * w0.x + a0.y * w0.y + a0.z * w0.z + a0.w * w0.w
              + a1.x * w1.x + a1.y * w1.y + a1.z * w1.z + a1.w * w1.w;
    acc = wave_reduce_sum(acc);
    if (lane == 0) qout[wid] = acc;
}

// scores[b][t] = sum_h tanh(q[b][h] + key[b][t][h]) * We[h]; one wave per row
__global__ void scores_kernel(const float* __restrict__ key,
                              const float* __restrict__ qb,
                              const float* __restrict__ We,
                              float* __restrict__ scores) {
    __shared__ float q_l[HH];
    __shared__ float w_l[HH];
    int row0 = blockIdx.x * 4;           // 4 waves per block, consecutive t
    int b = row0 >> 12;                  // / TT (block never straddles b)
    q_l[threadIdx.x]       = qb[(size_t)b * HH + threadIdx.x];
    q_l[threadIdx.x + 256] = qb[(size_t)b * HH + threadIdx.x + 256];
    w_l[threadIdx.x]       = We[threadIdx.x];
    w_l[threadIdx.x + 256] = We[threadIdx.x + 256];
    __syncthreads();

    int w = threadIdx.x >> 6, lane = threadIdx.x & 63;
    int row = row0 + w;
    const float4* kr = (const float4*)(key + (size_t)row * HH);
    float4 k0 = kr[lane];
    float4 k1 = kr[lane + 64];
    int h0 = lane * 4, h1 = 256 + lane * 4;
    float p = 0.f;
    p += fast_tanh(q_l[h0 + 0] + k0.x) * w_l[h0 + 0];
    p += fast_tanh(q_l[h0 + 1] + k0.y) * w_l[h0 + 1];
    p += fast_tanh(q_l[h0 + 2] + k0.z) * w_l[h0 + 2];
    p += fast_tanh(q_l[h0 + 3] + k0.w) * w_l[h0 + 3];
    p += fast_tanh(q_l[h1 + 0] + k1.x) * w_l[h1 + 0];
    p += fast_tanh(q_l[h1 + 1] + k1.y) * w_l[h1 + 1];
    p += fast_tanh(q_l[h1 + 2] + k1.z) * w_l[h1 + 2];
    p += fast_tanh(q_l[h1 + 3] + k1.w) * w_l[h1 + 3];
    p = wave_reduce_sum(p);
    if (lane == 0) scores[row] = p;
}

// in-place softmax over T per batch; one block per b, 1024 threads x 4 vals
__global__ void softmax_kernel(float* __restrict__ sc) {
    __shared__ float red_max[16];
    __shared__ float red_sum[16];
    float* row = sc + (size_t)blockIdx.x * TT;
    float4 v = ((float4*)row)[threadIdx.x];
    int wv = threadIdx.x >> 6, lane = threadIdx.x & 63;

    float m = fmaxf(fmaxf(v.x, v.y), fmaxf(v.z, v.w));
#pragma unroll
    for (int off = 32; off > 0; off >>= 1) m = fmaxf(m, __shfl_xor(m, off, 64));
    if (lane == 0) red_max[wv] = m;
    __syncthreads();
    m = red_max[0];
#pragma unroll
    for (int i = 1; i < 16; ++i) m = fmaxf(m, red_max[i]);

    float e0 = __expf(v.x - m), e1 = __expf(v.y - m);
    float e2 = __expf(v.z - m), e3 = __expf(v.w - m);
    float s = e0 + e1 + e2 + e3;
    s = wave_reduce_sum(s);
    if (lane == 0) red_sum[wv] = s;
    __syncthreads();
    s = 0.f;
#pragma unroll
    for (int i = 0; i < 16; ++i) s += red_sum[i];
    float inv = 1.f / s;
    ((float4*)row)[threadIdx.x] = make_float4(e0 * inv, e1 * inv, e2 * inv, e3 * inv);
}

// partial context: block = (b, ts); 128 threads x float4 = 512 d; CH rows
__global__ void ctx_partial_kernel(const float* __restrict__ value,
                                   const float* __restrict__ alphas,
                                   float* __restrict__ part) {
    int b = blockIdx.x / TS, ts = blockIdx.x % TS;
    int tid = threadIdx.x;  // 0..127
    const float4* vp = (const float4*)(value + ((size_t)b * TT + (size_t)ts * CH) * HH);
    const float*  ap = alphas + (size_t)b * TT + (size_t)ts * CH;
    float4 acc = make_float4(0.f, 0.f, 0.f, 0.f);
#pragma unroll 4
    for (int r = 0; r < CH; ++r) {
        float a = ap[r];
        float4 v = vp[(size_t)r * (HH / 4) + tid];
        acc.x += a * v.x; acc.y += a * v.y; acc.z += a * v.z; acc.w += a * v.w;
    }
    ((float4*)(part + ((size_t)(ts * BB + b)) * HH))[tid] = acc;
}

// context[b][d] = fixed-order sum of TS partials
__global__ void ctx_reduce_kernel(const float* __restrict__ part,
                                  float* __restrict__ ctx) {
    int i = blockIdx.x * blockDim.x + threadIdx.x;  // < BB*HH
    float s = 0.f;
#pragma unroll
    for (int ts = 0; ts < TS; ++ts) s += part[(size_t)ts * BB * HH + i];
    ctx[i] = s;
}

extern "C" void kernel_launch(void* const* d_in, const int* in_sizes, int n_in,
                              void* d_out, int out_size, void* d_ws, size_t ws_size,
                              hipStream_t stream) {
    const float* query = (const float*)d_in[0];
    const float* key   = (const float*)d_in[1];
    const float* value = (const float*)d_in[2];
    // d_in[3] = mask (unused by reference forward)
    const float* Wq    = (const float*)d_in[4];
    const float* We    = (const float*)d_in[5];

    float* ctx    = (float*)d_out;            // [B,1,H] = 16384 floats
    float* alphas = (float*)d_out + BB * HH;  // [B,T]   = 131072 floats

    float* qbuf = (float*)d_ws;               // B*H floats = 64 KiB
    float* part = qbuf + BB * HH;             // TS*B*H floats = 4 MiB

    // 1) q projection: B*H waves = 16384 -> 4096 blocks of 256
    qproj_kernel<<<(BB * HH) / 4, 256, 0, stream>>>(query, Wq, qbuf);
    // 2) scores: B*T rows, 4 rows/block
    scores_kernel<<<(BB * TT) / 4, 256, 0, stream>>>(key, qbuf, We, alphas);
    // 3) softmax in place -> alphas
    softmax_kernel<<<BB, 1024, 0, stream>>>(alphas);
    // 4) weighted-value partials
    ctx_partial_kernel<<<BB * TS, 128, 0, stream>>>(value, alphas, part);
    // 5) final reduce -> context
    ctx_reduce_kernel<<<(BB * HH) / 256, 256, 0, stream>>>(part, ctx);
}

// Round 2
// 109.023 us; speedup vs baseline: 1.1639x; 1.1639x over previous
//
#include <hip/hip_runtime.h>
#include <math.h>

#define BB 32
#define TT 4096
#define HH 512
#define QQS 512
#define TS 64            // chunks per batch
#define CH 64            // rows per chunk (TS*CH == TT)

__device__ inline float wave_reduce_sum(float v) {
#pragma unroll
    for (int off = 32; off > 0; off >>= 1) v += __shfl_xor(v, off, 64);
    return v;
}

__device__ inline float wave_reduce_max(float v) {
#pragma unroll
    for (int off = 32; off > 0; off >>= 1) v = fmaxf(v, __shfl_xor(v, off, 64));
    return v;
}

__device__ inline float fast_tanh(float x) {
    x = fminf(fmaxf(x, -15.f), 15.f);
    float e = __expf(-2.f * x);
    return (1.f - e) / (1.f + e);
}

// q[b][h] = sum_s query[b][s] * Wq[h][s]; one wave per (b,h)
__global__ void qproj_kernel(const float* __restrict__ query,
                             const float* __restrict__ Wq,
                             float* __restrict__ qout) {
    int wid  = (blockIdx.x * blockDim.x + threadIdx.x) >> 6;
    int lane = threadIdx.x & 63;
    int b = wid >> 9;        // / HH
    int h = wid & (HH - 1);
    const float4* qr = (const float4*)(query + (size_t)b * QQS);
    const float4* wr = (const float4*)(Wq + (size_t)h * QQS);
    float4 a0 = qr[lane],      w0 = wr[lane];
    float4 a1 = qr[lane + 64], w1 = wr[lane + 64];
    float acc = a0.x * w0.x + a0.y * w0.y + a0.z * w0.z + a0.w * w0.w
              + a1.x * w1.x + a1.y * w1.y + a1.z * w1.z + a1.w * w1.w;
    acc = wave_reduce_sum(acc);
    if (lane == 0) qout[wid] = acc;
}

// Fused: per (b, chunk) block -> scores, chunk softmax stats, partial context.
__global__ __launch_bounds__(256) void fused_kernel(
        const float* __restrict__ key, const float* __restrict__ value,
        const float* __restrict__ qb,  const float* __restrict__ We,
        float* __restrict__ scores, float* __restrict__ mbuf,
        float* __restrict__ zbuf,   float* __restrict__ part) {
    __shared__ float q_l[HH];
    __shared__ float w_l[HH];
    __shared__ float s_lds[CH];
    __shared__ float e_lds[CH];
    __shared__ float ctx_lds[HH];

    int b = blockIdx.x / TS, c = blockIdx.x % TS;
    int tid = threadIdx.x;
    q_l[tid]       = qb[(size_t)b * HH + tid];
    q_l[tid + 256] = qb[(size_t)b * HH + tid + 256];
    w_l[tid]       = We[tid];
    w_l[tid + 256] = We[tid + 256];
    __syncthreads();

    int w = tid >> 6, lane = tid & 63;
    size_t row0 = (size_t)b * TT + (size_t)c * CH;

    // Phase A: scores for CH rows; wave w does rows w, w+4, ...
    for (int rr = 0; rr < CH / 4; ++rr) {
        int r = rr * 4 + w;
        const float4* kr = (const float4*)(key + (row0 + r) * HH);
        float4 k0 = kr[lane];
        float4 k1 = kr[lane + 64];
        int h0 = lane * 4, h1 = 256 + lane * 4;
        float p = 0.f;
        p += fast_tanh(q_l[h0 + 0] + k0.x) * w_l[h0 + 0];
        p += fast_tanh(q_l[h0 + 1] + k0.y) * w_l[h0 + 1];
        p += fast_tanh(q_l[h0 + 2] + k0.z) * w_l[h0 + 2];
        p += fast_tanh(q_l[h0 + 3] + k0.w) * w_l[h0 + 3];
        p += fast_tanh(q_l[h1 + 0] + k1.x) * w_l[h1 + 0];
        p += fast_tanh(q_l[h1 + 1] + k1.y) * w_l[h1 + 1];
        p += fast_tanh(q_l[h1 + 2] + k1.z) * w_l[h1 + 2];
        p += fast_tanh(q_l[h1 + 3] + k1.w) * w_l[h1 + 3];
        p = wave_reduce_sum(p);
        if (lane == 0) s_lds[r] = p;
    }
    __syncthreads();

    // Phase B: wave 0 -> chunk max / exp / sum; wave 1 -> scores to global
    if (w == 0) {
        float s = s_lds[lane];
        float m = wave_reduce_max(s);
        float e = __expf(s - m);
        e_lds[lane] = e;
        float z = wave_reduce_sum(e);
        if (lane == 0) {
            mbuf[b * TS + c] = m;
            zbuf[b * TS + c] = z;
        }
    } else if (w == 1 && lane < CH / 4) {
        ((float4*)(scores + row0))[lane] = ((float4*)s_lds)[lane];
    }
    __syncthreads();

    // Phase C: exp-weighted partial context over the chunk's value rows
    int d4 = tid & 127, rg = tid >> 7;
    const float4* vp = (const float4*)(value + row0 * HH);
    float4 acc = make_float4(0.f, 0.f, 0.f, 0.f);
#pragma unroll 4
    for (int r = rg; r < CH; r += 2) {
        float a = e_lds[r];
        float4 v = vp[(size_t)r * (HH / 4) + d4];
        acc.x += a * v.x; acc.y += a * v.y; acc.z += a * v.z; acc.w += a * v.w;
    }
    if (rg == 0) ((float4*)ctx_lds)[d4] = acc;
    __syncthreads();
    if (rg == 1) {
        float4 t = ((float4*)ctx_lds)[d4];
        t.x += acc.x; t.y += acc.y; t.z += acc.z; t.w += acc.w;
        ((float4*)(part + ((size_t)c * BB + b) * HH))[d4] = t;
    }
}

// Finalize: blocks 0..31 -> alphas; blocks 32..95 -> context
__global__ void finalize_kernel(const float* __restrict__ scores,
                                const float* __restrict__ mbuf,
                                const float* __restrict__ zbuf,
                                const float* __restrict__ part,
                                float* __restrict__ alphas,
                                float* __restrict__ ctx) {
    int tid = threadIdx.x, lane = tid & 63;
    if (blockIdx.x < BB) {
        int b = blockIdx.x;
        // all 4 waves redundantly compute M, Z (lane < 64 == TS)
        float m_l = mbuf[b * TS + lane];
        float z_l = zbuf[b * TS + lane];
        float M = wave_reduce_max(m_l);
        float Z = wave_reduce_sum(__expf(m_l - M) * z_l);
        float invZ = 1.f / Z;
        const float4* sp = (const float4*)(scores + (size_t)b * TT);
        float4* ap = (float4*)(alphas + (size_t)b * TT);
#pragma unroll
        for (int i = 0; i < 4; ++i) {
            float4 s = sp[tid + i * 256];
            float4 a;
            a.x = __expf(s.x - M) * invZ;
            a.y = __expf(s.y - M) * invZ;
            a.z = __expf(s.z - M) * invZ;
            a.w = __expf(s.w - M) * invZ;
            ap[tid + i * 256] = a;
        }
    } else {
        int i = blockIdx.x - BB;     // 0..63
        int b = i >> 1;
        int d = (i & 1) * 256 + tid;
        __shared__ float scale[TS];
        if (tid < TS) {
            float m_l = mbuf[b * TS + lane];
            float z_l = zbuf[b * TS + lane];
            float M = wave_reduce_max(m_l);
            float Z = wave_reduce_sum(__expf(m_l - M) * z_l);
            scale[lane] = __expf(m_l - M) / Z;
        }
        __syncthreads();
        float s = 0.f;
#pragma unroll
        for (int c2 = 0; c2 < TS; ++c2)
            s += scale[c2] * part[((size_t)c2 * BB + b) * HH + d];
        ctx[(size_t)b * HH + d] = s;
    }
}

extern "C" void kernel_launch(void* const* d_in, const int* in_sizes, int n_in,
                              void* d_out, int out_size, void* d_ws, size_t ws_size,
                              hipStream_t stream) {
    const float* query = (const float*)d_in[0];
    const float* key   = (const float*)d_in[1];
    const float* value = (const float*)d_in[2];
    // d_in[3] = mask (unused by reference forward)
    const float* Wq    = (const float*)d_in[4];
    const float* We    = (const float*)d_in[5];

    float* ctx    = (float*)d_out;            // [B,1,H]
    float* alphas = (float*)d_out + BB * HH;  // [B,T]

    float* qbuf   = (float*)d_ws;                    // B*H
    float* sc     = qbuf + BB * HH;                  // B*T
    float* mbuf   = sc + BB * TT;                    // B*TS
    float* zbuf   = mbuf + BB * TS;                  // B*TS
    float* part   = zbuf + BB * TS;                  // TS*B*H

    qproj_kernel<<<(BB * HH) / 4, 256, 0, stream>>>(query, Wq, qbuf);
    fused_kernel<<<BB * TS, 256, 0, stream>>>(key, value, qbuf, We, sc, mbuf, zbuf, part);
    finalize_kernel<<<BB + 2 * BB, 256, 0, stream>>>(sc, mbuf, zbuf, part, alphas, ctx);
}